// Round 13
// baseline (251.385 us; speedup 1.0000x reference)
//
#include <hip/hip_runtime.h>

// Conv2dFusion v9: 1024-thread block (16 waves), fine-grained wave split.
// Per image: 128x128 rank-1 map
//   -> conv0(1->32) via MFMA f16 K=3 implicit GEMM (bursts of 8 pooled rows into
//      16-slot P0 ring every 4th iteration, units split across all 16 waves)
//   -> conv1(32->64)+GELU+pool: 8 waves = (nt x half), acc[4] each -> P1 6-row ring
//   -> conv2(64->64)+GELU+pool: 8 waves = (nt x mt), acc[2] each, even iters -> out.
// Round-12 evidence: both pipes <50% at Occupancy 22% (2 waves/SIMD) -> latency
// bound; LDS 124KB forbids 2 blocks/CU. v9 doubles waves INSIDE the block:
// same LDS, same per-wave registers (VGPR 124 <= 128 cap of 4 waves/SIMD),
// half the per-wave work per barrier. Math per output unchanged (bit-identical).
// Register lessons kept: no waves_per_eu forcing; watch FETCH_SIZE for spills.

typedef short short8 __attribute__((ext_vector_type(8)));
typedef _Float16 half8 __attribute__((ext_vector_type(8)));
typedef float f32x4 __attribute__((ext_vector_type(4)));
typedef unsigned int uint4v __attribute__((ext_vector_type(4)));

#define OFF_TY   0                     // f32[132] = 528 B (rounded to 544)
#define OFF_H16  544                   // (126*32) * 8 B (f16 h0,h1,h2,pad) = 32256
#define OFF_P0   32800                 // 16 slots * 264 units * 16 B = 67584
#define OFF_P1   100384                // 1472 units * 16 B = 23552
#define OFF_TK   OFF_P0                // f32[128] staging, dead before first P0 write
#define LDS_TOTAL 123936

__device__ __forceinline__ unsigned short f2bf(float f) {
    unsigned int u = __float_as_uint(f);
    u += 0x7fffu + ((u >> 16) & 1u);   // RNE
    return (unsigned short)(u >> 16);
}

__device__ __forceinline__ unsigned int pack2h(float a, float b) {
    union { _Float16 h[2]; unsigned int u; } p;
    p.h[0] = (_Float16)a;
    p.h[1] = (_Float16)b;
    return p.u;
}

// erf-GELU via A&S 7.1.25 (|err| <= 2.5e-5), branch-free.
__device__ __forceinline__ float gelu_f(float x) {
    float ax = __builtin_fabsf(x);
    float E  = __builtin_amdgcn_exp2f(x * x * -0.72134752f);
    float k  = __builtin_amdgcn_rcpf(__builtin_fmaf(0.33267686f, ax, 1.0f));
    float s  = __builtin_fmaf(0.7478556f, k, -0.0958798f);
    s = __builtin_fmaf(s, k, 0.3480242f);
    s = s * k;
    float erfabs = __builtin_fmaf(-s, E, 1.0f);
    return __builtin_fmaf(0.5f * ax, erfabs, 0.5f * x);
}

// conv0 burst: pooled rows pbase..pbase+7 via MFMA f16 (see v8 header comment).
// 126 units = (x-pair 0..62) x (ctile 0..1); conv1 waves (w<8) take 6 each,
// conv2 waves take 10 (w=8..14) / 8 (w=15) -- conv2 waves idle on odd iters.
__device__ __forceinline__ void conv0_burst(char* smem, const float* tys,
                                            int w, int l15, int lc,
                                            float b00, float b01, int pbase) {
    const int y_base = 2 * pbase;
    half8 afrag;
    {
        float a0 = tys[y_base + l15 + 0];
        float a1 = tys[y_base + l15 + 1];
        float a2 = tys[y_base + l15 + 2];
        float a3 = tys[y_base + l15 + 3];
        union { uint4v u; half8 h; } av;
        av.u = (uint4v){ pack2h(a0, a1), pack2h(a2, a3), 0u, 0u };
        afrag = av.h;   // lanes lc!=0 hold k>=8: B is zero there
    }
    const f32x4 ci0 = (f32x4){b00, b00, b00, b00};
    const f32x4 ci1 = (f32x4){b01, b01, b01, b01};
    const int base = (w < 8) ? w * 6 : 48 + (w - 8) * 10;
    const int cnt  = (w < 8) ? 6 : ((w == 15) ? 8 : 10);

    #pragma unroll
    for (int j = 0; j < 10; ++j) {
        if (j < cnt) {
            const int uid = base + j;
            const int q  = uid >> 1;
            const int ct = uid & 1;
            const char* hp = smem + OFF_H16 + ((2*q)*32 + ct*16 + l15) * 8;
            uint2 hA = *(const uint2*)(hp);
            uint2 hB = *(const uint2*)(hp + 256);   // x+1 row
            if (lc != 0) { hA.x = 0u; hA.y = 0u; hB.x = 0u; hB.y = 0u; }
            union { uint4v u; half8 h; } ba, bb;
            ba.u = (uint4v){hA.x, hA.y, 0u, 0u};
            bb.u = (uint4v){hB.x, hB.y, 0u, 0u};
            const f32x4 ci = ct ? ci1 : ci0;
            f32x4 cA = __builtin_amdgcn_mfma_f32_16x16x32_f16(afrag, ba.h, ci, 0, 0, 0);
            f32x4 cB = __builtin_amdgcn_mfma_f32_16x16x32_f16(afrag, bb.h, ci, 0, 0, 0);
            float m0 = gelu_f(fmaxf(fmaxf(cA[0], cA[1]), fmaxf(cB[0], cB[1])));
            float m1 = gelu_f(fmaxf(fmaxf(cA[2], cA[3]), fmaxf(cB[2], cB[3])));
            const int c = ct * 16 + l15;
            const int upos = (q >> 1) * 8 + ((4 * (q & 1) + (c >> 3)) ^ ((q >> 1) & 7));
            const int p0 = pbase + 2 * lc;
            const int s0 = p0 & 15, s1 = (p0 + 1) & 15;
            *(unsigned short*)(smem + OFF_P0 + (s0 * 264 + upos) * 16 + (c & 7) * 2) = f2bf(m0);
            *(unsigned short*)(smem + OFF_P0 + (s1 * 264 + upos) * 16 + (c & 7) * 2) = f2bf(m1);
        }
    }
}

__launch_bounds__(1024, 1)
__global__ void conv_pipeline(const float* __restrict__ token,
                              const float* __restrict__ type_,
                              const float* __restrict__ w0, const float* __restrict__ b0,
                              const float* __restrict__ w1, const float* __restrict__ b1,
                              const float* __restrict__ w2, const float* __restrict__ b2,
                              float* __restrict__ out) {
    extern __shared__ char smem[];
    float* tys = (float*)(smem + OFF_TY);
    float* tks = (float*)(smem + OFF_TK);

    const int tid = threadIdx.x;
    const int img = blockIdx.x;
    const int w   = tid >> 6;          // 0..15
    const int l   = tid & 63;
    const int l15 = l & 15;
    const int lc  = l >> 4;
    const int c0w = tid & 31;

    for (int i = tid; i < 132; i += 1024) {
        tys[i] = (i < 128) ? type_[img*128 + i] : 0.f;
        if (i < 128) tks[i] = token[img*128 + i];
    }

    const float b00 = b0[l15];
    const float b01 = b0[l15 + 16];

    __syncthreads();   // ty/tk visible

    // H16[x][c] = (h0,h1,h2,0) f16, h_u = sum_v w0[c,u,v]*tk[x+v]
    {
        float w0r[9];
        #pragma unroll
        for (int i = 0; i < 9; ++i) w0r[i] = w0[c0w*9 + i];
        int x = tid >> 5;              // 0..31
        #pragma unroll
        for (int k = 0; k < 4; ++k, x += 32) {
            if (x < 126) {
                float t0 = tks[x], t1 = tks[x+1], t2 = tks[x+2];
                float h0 = __builtin_fmaf(w0r[0],t0, __builtin_fmaf(w0r[1],t1, w0r[2]*t2));
                float h1 = __builtin_fmaf(w0r[3],t0, __builtin_fmaf(w0r[4],t1, w0r[5]*t2));
                float h2 = __builtin_fmaf(w0r[6],t0, __builtin_fmaf(w0r[7],t1, w0r[8]*t2));
                uint2 hv; hv.x = pack2h(h0, h1); hv.y = pack2h(h2, 0.f);
                *(uint2*)(smem + OFF_H16 + (x*32 + c0w)*8) = hv;
            }
        }
    }

    // Weight fragments: conv1 waves (w<8) use wf[0..8] (nt=w&3);
    // conv2 waves (w>=8) use wf[0..17] (nt=w&3, kh*9+uv).
    short8 wf[18];
    float bias;
    const int ch = ((w & 3) * 16) + l15;
    if (w < 8) {
        bias = b1[ch];
        #pragma unroll
        for (int uv = 0; uv < 9; ++uv) {
            short8 f;
            #pragma unroll
            for (int j = 0; j < 8; ++j)
                f[j] = (short)f2bf(w1[(ch*32 + 8*lc + j)*9 + uv]);
            wf[uv] = f;
        }
    } else {
        bias = b2[ch];
        #pragma unroll
        for (int kh = 0; kh < 2; ++kh)
            #pragma unroll
            for (int uv = 0; uv < 9; ++uv) {
                short8 f;
                #pragma unroll
                for (int j = 0; j < 8; ++j)
                    f[j] = (short)f2bf(w2[(ch*64 + kh*32 + 8*lc + j)*9 + uv]);
                wf[kh*9 + uv] = f;
            }
    }

    __syncthreads();   // H16 visible; tks dead (aliases P0)

    conv0_burst(smem, tys, w, l15, lc, b00, b01, 0);   // pooled rows 0..7
    __syncthreads();

    const size_t obase = (size_t)img * 12544;

    for (int i1 = 0; i1 < 30; ++i1) {
        if (w < 8) {
            // ---------- conv1 row i1: wave = (nt=w&3, half=w>>2), acc[4] ----------
            const int half = w >> 2;
            int rbase = (i1 % 6) * 30;
            int xr = ch >> 3;
            f32x4 acc[4];
            #pragma unroll
            for (int i = 0; i < 4; ++i) acc[i] = (f32x4){0.f,0.f,0.f,0.f};
            #pragma unroll
            for (int pr = 0; pr < 4; ++pr) {
                int sbase = ((2*i1 + pr) & 15) * 264;
                #pragma unroll
                for (int v = 0; v < 3; ++v) {
                    #pragma unroll
                    for (int mtl = 0; mtl < 2; ++mtl) {
                        int col = (2*half + mtl)*16 + l15 + v;
                        int unit = sbase + (col>>1)*8 + ((4*(col&1) + lc) ^ ((col>>1)&7));
                        short8 a = *(const short8*)(smem + OFF_P0 + unit*16);
                        if (pr <= 2)
                            acc[mtl*2+0] = __builtin_amdgcn_mfma_f32_16x16x32_bf16(
                                a, wf[pr*3+v], acc[mtl*2+0], 0, 0, 0);
                        if (pr >= 1)
                            acc[mtl*2+1] = __builtin_amdgcn_mfma_f32_16x16x32_bf16(
                                a, wf[(pr-1)*3+v], acc[mtl*2+1], 0, 0, 0);
                    }
                }
            }
            #pragma unroll
            for (int mtl = 0; mtl < 2; ++mtl) {
                int pcol = (2*half + mtl)*8 + lc*2;
                if (pcol < 30) {
                    f32x4 A0 = acc[mtl*2+0], A1 = acc[mtl*2+1];
                    float p0 = fmaxf(fmaxf(A0[0], A0[1]), fmaxf(A1[0], A1[1]));
                    float p1 = fmaxf(fmaxf(A0[2], A0[3]), fmaxf(A1[2], A1[3]));
                    float m0 = gelu_f(p0 + bias);
                    float m1 = gelu_f(p1 + bias);
                    int u0 = (rbase + pcol)*8     + (xr ^ (pcol & 7));
                    int u1 = (rbase + pcol + 1)*8 + (xr ^ ((pcol+1) & 7));
                    *(unsigned short*)(smem + OFF_P1 + u0*16 + (ch&7)*2) = f2bf(m0);
                    *(unsigned short*)(smem + OFF_P1 + u1*16 + (ch&7)*2) = f2bf(m1);
                }
            }
        } else if (i1 >= 4 && (i1 & 1) == 0) {
            // ---------- conv2 row i2: wave = (nt=w&3, mt=(w>>2)&1), acc[2] ----------
            const int i2 = (i1 - 4) >> 1;
            const int mt = (w >> 2) & 1;
            f32x4 acc0 = (f32x4){0.f,0.f,0.f,0.f};
            f32x4 acc1 = (f32x4){0.f,0.f,0.f,0.f};
            #pragma unroll
            for (int pr = 0; pr < 4; ++pr) {
                int rb = ((2*i2 + pr) % 6) * 30;
                #pragma unroll
                for (int v = 0; v < 3; ++v) {
                    int col = mt*16 + l15 + v;
                    #pragma unroll
                    for (int kh = 0; kh < 2; ++kh) {
                        int unit = (rb + col)*8 + ((kh*4 + lc) ^ (col & 7));
                        short8 a = *(const short8*)(smem + OFF_P1 + unit*16);
                        if (pr <= 2)
                            acc0 = __builtin_amdgcn_mfma_f32_16x16x32_bf16(
                                a, wf[kh*9 + pr*3+v], acc0, 0, 0, 0);
                        if (pr >= 1)
                            acc1 = __builtin_amdgcn_mfma_f32_16x16x32_bf16(
                                a, wf[kh*9 + (pr-1)*3+v], acc1, 0, 0, 0);
                    }
                }
            }
            int pcol = mt*8 + lc*2;
            if (pcol < 14) {
                float g00 = gelu_f(acc0[0] + bias), g01 = gelu_f(acc0[1] + bias);
                float g02 = gelu_f(acc0[2] + bias), g03 = gelu_f(acc0[3] + bias);
                float g10 = gelu_f(acc1[0] + bias), g11 = gelu_f(acc1[1] + bias);
                float g12 = gelu_f(acc1[2] + bias), g13 = gelu_f(acc1[3] + bias);
                float m0 = fmaxf(fmaxf(g00, g01), fmaxf(g10, g11));
                float m1 = fmaxf(fmaxf(g02, g03), fmaxf(g12, g13));
                float2 st; st.x = m0; st.y = m1;
                *(float2*)(out + obase + ch*196 + i2*14 + pcol) = st;
            }
        }

        // conv0 burst every 4th iter: pooled rows 2i1+4..2i1+11 (slots disjoint
        // from this iteration's conv1 read slots (2i1..2i1+3)&15).
        if ((i1 & 3) == 2) conv0_burst(smem, tys, w, l15, lc, b00, b01, 2*i1 + 4);

        __syncthreads();
    }

    // tail: conv2 row 13 (P1 rows 26..29)
    if (w >= 8) {
        const int i2 = 13;
        const int mt = (w >> 2) & 1;
        f32x4 acc0 = (f32x4){0.f,0.f,0.f,0.f};
        f32x4 acc1 = (f32x4){0.f,0.f,0.f,0.f};
        #pragma unroll
        for (int pr = 0; pr < 4; ++pr) {
            int rb = ((2*i2 + pr) % 6) * 30;
            #pragma unroll
            for (int v = 0; v < 3; ++v) {
                int col = mt*16 + l15 + v;
                #pragma unroll
                for (int kh = 0; kh < 2; ++kh) {
                    int unit = (rb + col)*8 + ((kh*4 + lc) ^ (col & 7));
                    short8 a = *(const short8*)(smem + OFF_P1 + unit*16);
                    if (pr <= 2)
                        acc0 = __builtin_amdgcn_mfma_f32_16x16x32_bf16(
                            a, wf[kh*9 + pr*3+v], acc0, 0, 0, 0);
                    if (pr >= 1)
                        acc1 = __builtin_amdgcn_mfma_f32_16x16x32_bf16(
                            a, wf[kh*9 + (pr-1)*3+v], acc1, 0, 0, 0);
                }
            }
        }
        int pcol = mt*8 + lc*2;
        if (pcol < 14) {
            float g00 = gelu_f(acc0[0] + bias), g01 = gelu_f(acc0[1] + bias);
            float g02 = gelu_f(acc0[2] + bias), g03 = gelu_f(acc0[3] + bias);
            float g10 = gelu_f(acc1[0] + bias), g11 = gelu_f(acc1[1] + bias);
            float g12 = gelu_f(acc1[2] + bias), g13 = gelu_f(acc1[3] + bias);
            float m0 = fmaxf(fmaxf(g00, g01), fmaxf(g10, g11));
            float m1 = fmaxf(fmaxf(g02, g03), fmaxf(g12, g13));
            float2 st; st.x = m0; st.y = m1;
            *(float2*)(out + obase + ch*196 + i2*14 + pcol) = st;
        }
    }
}

extern "C" void kernel_launch(void* const* d_in, const int* in_sizes, int n_in,
                              void* d_out, int out_size, void* d_ws, size_t ws_size,
                              hipStream_t stream) {
    const float* token = (const float*)d_in[0];
    const float* type_ = (const float*)d_in[1];
    const float* w0 = (const float*)d_in[2];
    const float* b0 = (const float*)d_in[3];
    const float* w1 = (const float*)d_in[4];
    const float* b1 = (const float*)d_in[5];
    const float* w2 = (const float*)d_in[6];
    const float* b2 = (const float*)d_in[7];
    float* out = (float*)d_out;

    hipLaunchKernelGGL(conv_pipeline, dim3(512), dim3(1024), LDS_TOTAL, stream,
                       token, type_, w0, b0, w1, b1, w2, b2, out);
}